// Round 3
// baseline (3355.643 us; speedup 1.0000x reference)
//
#include <hip/hip_runtime.h>

#define NODES  50000
#define EDGES  800000
#define GRAPHS 1024
#define P      200      // uniform row pitch (floats) for node-feature buffers

// ---------------------------------------------------------------------------
// CSR build
// ---------------------------------------------------------------------------
__global__ void hist_kernel(const int* __restrict__ dst, int* __restrict__ deg) {
    int e = blockIdx.x * blockDim.x + threadIdx.x;
    if (e < EDGES) atomicAdd(&deg[dst[e]], 1);
}

__global__ void scan_kernel(const int* __restrict__ deg,
                            int* __restrict__ rowstart, int* __restrict__ cursor) {
    __shared__ int part[1024];
    int t = threadIdx.x;
    const int CH = (NODES + 1023) / 1024;   // 49
    int base = t * CH;
    int s = 0;
    for (int i = 0; i < CH; i++) {
        int n = base + i;
        if (n < NODES) s += deg[n];
    }
    part[t] = s;
    __syncthreads();
    for (int off = 1; off < 1024; off <<= 1) {
        int v = 0;
        if (t >= off) v = part[t - off];
        __syncthreads();
        if (t >= off) part[t] += v;
        __syncthreads();
    }
    int run = (t == 0) ? 0 : part[t - 1];
    for (int i = 0; i < CH; i++) {
        int n = base + i;
        if (n < NODES) {
            rowstart[n] = run;
            cursor[n]   = run;
            run += deg[n];
        }
    }
    if (t == 0) rowstart[NODES] = EDGES;
}

__global__ void scatter_kernel(const int* __restrict__ src, const int* __restrict__ dst,
                               int* __restrict__ cursor, int* __restrict__ csrc) {
    int e = blockIdx.x * blockDim.x + threadIdx.x;
    if (e < EDGES) {
        int p = atomicAdd(&cursor[dst[e]], 1);
        csrc[p] = src[e];
    }
}

// ---------------------------------------------------------------------------
// Weight pad: dst[k][n] (pitch NP=2^npshift) = src[k][n] or 0
// ---------------------------------------------------------------------------
__global__ void pad_w_kernel(const float* __restrict__ src, int K, int N, int npshift,
                             float* __restrict__ dst) {
    int idx = blockIdx.x * blockDim.x + threadIdx.x;
    int NP = 1 << npshift;
    if (idx >= K * NP) return;
    int k = idx >> npshift, n = idx & (NP - 1);
    dst[idx] = (n < N) ? src[k * N + n] : 0.0f;
}

// ---------------------------------------------------------------------------
// Aggregation: one wave per destination node, register accumulation, no atomics
// ---------------------------------------------------------------------------
template<int D>
__global__ void csr_agg(const float* __restrict__ feat, int fpitch,
                        const int* __restrict__ rowstart, const int* __restrict__ csrc,
                        float* __restrict__ agg) {
    int wid  = (blockIdx.x * blockDim.x + threadIdx.x) >> 6;
    int lane = threadIdx.x & 63;
    if (wid >= NODES) return;
    constexpr int NI = (D + 63) / 64;
    float s[NI];
#pragma unroll
    for (int i = 0; i < NI; i++) s[i] = 0.0f;
    int r0 = rowstart[wid], r1 = rowstart[wid + 1];
    for (int r = r0; r < r1; r++) {
        int sn = csrc[r];
        const float* fp = feat + (size_t)sn * fpitch;
#pragma unroll
        for (int i = 0; i < NI; i++) {
            int c = lane + 64 * i;
            if (c < D) s[i] += fp[c];
        }
    }
    float* ap = agg + (size_t)wid * P;
#pragma unroll
    for (int i = 0; i < NI; i++) {
        int c = lane + 64 * i;
        if (c < D) ap[c] = s[i];
    }
}

// ---------------------------------------------------------------------------
// GEMM: OUT[m][n] = relu( (X[m]+A2[m]) @ W + B ), optional BN-stat epilogue.
// 64-row tile / block. W pre-padded to pitch NP (zeros beyond N).
// Register-staged prefetch: issue chunk c+1 global loads before computing
// chunk c; LDS write after the post-compute barrier.
// In-place OUT==A2 safe: reads of own rows all precede epilogue writes.
// ---------------------------------------------------------------------------
template<int K, int N, bool ADD2, bool STATS>
__launch_bounds__(256, 2)
__global__ void gemm_kernel(const float* __restrict__ X, int xpitch,
                            const float* __restrict__ A2,
                            const float* __restrict__ WP,   // K x NP, padded
                            const float* __restrict__ B,
                            float* __restrict__ OUT,
                            float* __restrict__ gsum, float* __restrict__ gsq) {
    constexpr int KT = 32;
    constexpr int NC = (K + KT - 1) / KT;
    constexpr int NP = ((N + 63) / 64) * 64;       // 64 or 256
    constexpr int G  = NP / 64;
    constexpr int AS = 36;                          // As row stride (bank-friendly)
    constexpr int NP4 = NP / 4;                     // float4s per W row
    constexpr int WIT = (KT * NP4) / 256;           // W float4 loads/thread: 8 or 2
    __shared__ __align__(16) float As[64 * AS];
    __shared__ __align__(16) float Ws[KT * NP];
    __shared__ float shSum[STATS ? NP : 4];
    __shared__ float shSq [STATS ? NP : 4];

    const int tid = threadIdx.x;
    const int tx = tid & 15, ty = tid >> 4;
    const int node0 = blockIdx.x * 64;

    if (STATS && tid < NP) { shSum[tid] = 0.0f; shSq[tid] = 0.0f; }

    float acc[4][G][4];
#pragma unroll
    for (int g = 0; g < G; g++) {
#pragma unroll
        for (int e = 0; e < 4; e++) {
            int n = tx * 4 + 64 * g + e;
            float bv = (n < N) ? B[n] : 0.0f;
#pragma unroll
            for (int i = 0; i < 4; i++) acc[i][g][e] = bv;
        }
    }

    float  aReg[8];
    float4 wReg[WIT];

    auto issueLoads = [&](int c) {
#pragma unroll
        for (int it = 0; it < 8; it++) {
            int idx = tid + 256 * it;
            int r = idx >> 5, cc = idx & 31;
            int gn = node0 + r, gk = c * KT + cc;
            float v = 0.0f;
            if (gn < NODES && gk < K) {
                v = X[(size_t)gn * xpitch + gk];
                if (ADD2) v += A2[(size_t)gn * P + gk];
            }
            aReg[it] = v;
        }
#pragma unroll
        for (int it = 0; it < WIT; it++) {
            int idx4 = tid + 256 * it;
            int kk = idx4 / NP4, n4 = idx4 % NP4;
            int gk = c * KT + kk;
            float4 v = make_float4(0.0f, 0.0f, 0.0f, 0.0f);
            if (gk < K) v = *(const float4*)&WP[gk * NP + n4 * 4];
            wReg[it] = v;
        }
    };
    auto writeLDS = [&]() {
#pragma unroll
        for (int it = 0; it < 8; it++) {
            int idx = tid + 256 * it;
            As[(idx >> 5) * AS + (idx & 31)] = aReg[it];
        }
#pragma unroll
        for (int it = 0; it < WIT; it++) {
            int idx4 = tid + 256 * it;
            *(float4*)&Ws[(idx4 / NP4) * NP + (idx4 % NP4) * 4] = wReg[it];
        }
    };

    issueLoads(0);
    writeLDS();
    __syncthreads();

    for (int c = 0; c < NC; c++) {
        if (c + 1 < NC) issueLoads(c + 1);      // prefetch overlaps compute

#pragma unroll
        for (int kk = 0; kk < KT; kk += 4) {
            float a[4][4];
#pragma unroll
            for (int i = 0; i < 4; i++) {
                float4 av = *(const float4*)&As[(ty + 16 * i) * AS + kk];
                a[i][0] = av.x; a[i][1] = av.y; a[i][2] = av.z; a[i][3] = av.w;
            }
#pragma unroll
            for (int q = 0; q < 4; q++) {
#pragma unroll
                for (int g = 0; g < G; g++) {
                    float4 w = *(const float4*)&Ws[(kk + q) * NP + tx * 4 + 64 * g];
#pragma unroll
                    for (int i = 0; i < 4; i++) {
                        acc[i][g][0] = fmaf(a[i][q], w.x, acc[i][g][0]);
                        acc[i][g][1] = fmaf(a[i][q], w.y, acc[i][g][1]);
                        acc[i][g][2] = fmaf(a[i][q], w.z, acc[i][g][2]);
                        acc[i][g][3] = fmaf(a[i][q], w.w, acc[i][g][3]);
                    }
                }
            }
        }
        __syncthreads();
        if (c + 1 < NC) {
            writeLDS();
            __syncthreads();
        }
    }

    // ---- epilogue: relu, float4 store, stats ----
#pragma unroll
    for (int g = 0; g < G; g++) {
        int nb = tx * 4 + 64 * g;
        float rv[4][4];
#pragma unroll
        for (int i = 0; i < 4; i++)
#pragma unroll
            for (int e = 0; e < 4; e++) rv[i][e] = fmaxf(acc[i][g][e], 0.0f);
#pragma unroll
        for (int i = 0; i < 4; i++) {
            int gn = node0 + ty + 16 * i;
            if (gn < NODES) {
                if (nb + 3 < N) {
                    *(float4*)&OUT[(size_t)gn * P + nb] =
                        make_float4(rv[i][0], rv[i][1], rv[i][2], rv[i][3]);
                } else {
#pragma unroll
                    for (int e = 0; e < 4; e++)
                        if (nb + e < N) OUT[(size_t)gn * P + nb + e] = rv[i][e];
                }
            }
        }
        if (STATS) {
#pragma unroll
            for (int e = 0; e < 4; e++) {
                int n = nb + e;
                if (n < N) {
                    float s = 0.0f, q = 0.0f;
#pragma unroll
                    for (int i = 0; i < 4; i++) {
                        if (node0 + ty + 16 * i < NODES) {
                            s += rv[i][e]; q += rv[i][e] * rv[i][e];
                        }
                    }
                    atomicAdd(&shSum[n], s); atomicAdd(&shSq[n], q);
                }
            }
        }
    }
    if (STATS) {
        __syncthreads();
        for (int n = tid; n < N; n += 256) {
            atomicAdd(&gsum[n], shSum[n]);
            atomicAdd(&gsq[n], shSq[n]);
        }
    }
}

// ---------------------------------------------------------------------------
// BN finalize + apply
// ---------------------------------------------------------------------------
template<int N>
__global__ void bn_finalize(const float* __restrict__ sum, const float* __restrict__ sq,
                            const float* __restrict__ gamma, const float* __restrict__ beta,
                            float* __restrict__ scale, float* __restrict__ shift) {
    int n = threadIdx.x;
    if (n < N) {
        float mean = sum[n] * (1.0f / NODES);
        float var  = sq[n] * (1.0f / NODES) - mean * mean;
        var = var < 0.0f ? 0.0f : var;
        float sc = gamma[n] * rsqrtf(var + 1e-5f);
        scale[n] = sc;
        shift[n] = beta[n] - mean * sc;
    }
}

template<int N>
__global__ void bn_apply(float* __restrict__ h, const float* __restrict__ scale,
                         const float* __restrict__ shift) {
    long idx = (long)blockIdx.x * blockDim.x + threadIdx.x;
    if (idx >= (long)NODES * N) return;
    int node = (int)(idx / N);
    int c = (int)(idx - (long)node * N);
    size_t o = (size_t)node * P + c;
    h[o] = fmaf(h[o], scale[c], shift[c]);
}

// ---------------------------------------------------------------------------
// Pool + head MLP
// ---------------------------------------------------------------------------
__global__ void pool_kernel(const float* __restrict__ h, const int* __restrict__ batch,
                            float* __restrict__ g) {
    int idx = blockIdx.x * blockDim.x + threadIdx.x;
    if (idx >= NODES * 32) return;
    int n = idx >> 5, f = idx & 31;
    atomicAdd(&g[batch[n] * 32 + f], h[(size_t)n * P + f]);
}

__global__ void head_kernel(const float* __restrict__ g,
                            const float* __restrict__ fw1, const float* __restrict__ fb1,
                            const float* __restrict__ fw2, const float* __restrict__ fb2,
                            const float* __restrict__ ow, const float* __restrict__ ob,
                            float* __restrict__ out) {
    int gi = blockIdx.x * blockDim.x + threadIdx.x;
    if (gi >= GRAPHS) return;
    float v[32];
#pragma unroll
    for (int k = 0; k < 32; k++) v[k] = g[gi * 32 + k];
    float a1[16];
#pragma unroll
    for (int o = 0; o < 16; o++) {
        float s = fb1[o];
#pragma unroll
        for (int k = 0; k < 32; k++) s = fmaf(v[k], fw1[k * 16 + o], s);
        a1[o] = s > 0.0f ? s : 0.0f;
    }
    float a2[8];
#pragma unroll
    for (int o = 0; o < 8; o++) {
        float s = fb2[o];
#pragma unroll
        for (int k = 0; k < 16; k++) s = fmaf(a1[k], fw2[k * 8 + o], s);
        a2[o] = s > 0.0f ? s : 0.0f;
    }
#pragma unroll
    for (int o = 0; o < 2; o++) {
        float s = ob[o];
#pragma unroll
        for (int k = 0; k < 8; k++) s = fmaf(a2[k], ow[k * 2 + o], s);
        out[gi * 2 + o] = s;
    }
}

// ---------------------------------------------------------------------------
extern "C" void kernel_launch(void* const* d_in, const int* in_sizes, int n_in,
                              void* d_out, int out_size, void* d_ws, size_t ws_size,
                              hipStream_t stream) {
    const float* x     = (const float*)d_in[0];
    const int*   ei    = (const int*)d_in[1];
    const int*   batch = (const int*)d_in[2];
    const float *w1a = (const float*)d_in[3],  *b1a = (const float*)d_in[4];
    const float *w1b = (const float*)d_in[5],  *b1b = (const float*)d_in[6];
    const float *g1  = (const float*)d_in[7],  *be1 = (const float*)d_in[8];
    const float *w2a = (const float*)d_in[9],  *b2a = (const float*)d_in[10];
    const float *w2b = (const float*)d_in[11], *b2b = (const float*)d_in[12];
    const float *g2  = (const float*)d_in[13], *be2 = (const float*)d_in[14];
    const float *w3a = (const float*)d_in[15], *b3a = (const float*)d_in[16];
    const float *w3b = (const float*)d_in[17], *b3b = (const float*)d_in[18];
    const float *g3  = (const float*)d_in[19], *be3 = (const float*)d_in[20];
    const float *fw1 = (const float*)d_in[21], *fb1 = (const float*)d_in[22];
    const float *fw2 = (const float*)d_in[23], *fb2 = (const float*)d_in[24];
    const float *ow  = (const float*)d_in[25], *ob  = (const float*)d_in[26];
    const int* src = ei;
    const int* dst = ei + EDGES;

    float* ws    = (float*)d_ws;
    float* AGG   = ws;                                  // 50000 x 200
    float* H     = ws + (size_t)NODES * P;              // 50000 x 200
    float* SUM   = ws + (size_t)2 * NODES * P;          // 256
    float* SQ    = SUM + 256;
    float* SCALE = SUM + 512;
    float* SHIFT = SUM + 768;
    float* G     = SUM + 1024;                          // 1024 x 32
    int*   deg      = (int*)(G + GRAPHS * 32);          // 50000
    int*   rowstart = deg + NODES;                      // 50001
    int*   cursor   = rowstart + NODES + 1;             // 50000
    int*   csrc     = cursor + NODES;                   // 800000
    float* WP1 = (float*)(csrc + EDGES);                // 114 x 256
    float* WP2 = WP1 + 114 * 256;                       // 198 x 256
    float* WP3 = WP2 + 198 * 256;                       // 198 x 64
    float* WP4 = WP3 + 198 * 64;                        // 64 x 64
    float* WP5 = WP4 + 64 * 64;                         // 64 x 64
    float* WP6 = WP5 + 64 * 64;                         // 32 x 64
    float* out = (float*)d_out;

    const int GB = (NODES + 63) / 64;        // gemm blocks
    const int AB = (NODES * 64 + 255) / 256; // agg blocks (wave per node)
    const int EB = (EDGES + 255) / 256;

    // ---- weight padding (once per launch) ----
    pad_w_kernel<<<(114 * 256 + 255) / 256, 256, 0, stream>>>(w1a, 114, 198, 8, WP1);
    pad_w_kernel<<<(198 * 256 + 255) / 256, 256, 0, stream>>>(w1b, 198, 198, 8, WP2);
    pad_w_kernel<<<(198 * 64 + 255) / 256, 256, 0, stream>>>(w2a, 198, 64, 6, WP3);
    pad_w_kernel<<<(64 * 64 + 255) / 256, 256, 0, stream>>>(w2b, 64, 64, 6, WP4);
    pad_w_kernel<<<(64 * 64 + 255) / 256, 256, 0, stream>>>(w3a, 64, 32, 6, WP5);
    pad_w_kernel<<<(32 * 64 + 255) / 256, 256, 0, stream>>>(w3b, 32, 32, 6, WP6);

    // ---- CSR build (shared by all 3 layers) ----
    hipMemsetAsync(deg, 0, NODES * sizeof(int), stream);
    hist_kernel<<<EB, 256, 0, stream>>>(dst, deg);
    scan_kernel<<<1, 1024, 0, stream>>>(deg, rowstart, cursor);
    scatter_kernel<<<EB, 256, 0, stream>>>(src, dst, cursor, csrc);

    // ---- layer 1 (114 -> 198 -> 198) ----
    csr_agg<114><<<AB, 256, 0, stream>>>(x, 114, rowstart, csrc, AGG);
    gemm_kernel<114, 198, true, false><<<GB, 256, 0, stream>>>(x, 114, AGG, WP1, b1a, AGG, nullptr, nullptr);
    hipMemsetAsync(SUM, 0, 512 * sizeof(float), stream);
    gemm_kernel<198, 198, false, true><<<GB, 256, 0, stream>>>(AGG, P, nullptr, WP2, b1b, H, SUM, SQ);
    bn_finalize<198><<<1, 256, 0, stream>>>(SUM, SQ, g1, be1, SCALE, SHIFT);
    bn_apply<198><<<(NODES * 198 + 255) / 256, 256, 0, stream>>>(H, SCALE, SHIFT);

    // ---- layer 2 (198 -> 64 -> 64) ----
    csr_agg<198><<<AB, 256, 0, stream>>>(H, P, rowstart, csrc, AGG);
    gemm_kernel<198, 64, true, false><<<GB, 256, 0, stream>>>(H, P, AGG, WP3, b2a, AGG, nullptr, nullptr);
    hipMemsetAsync(SUM, 0, 512 * sizeof(float), stream);
    gemm_kernel<64, 64, false, true><<<GB, 256, 0, stream>>>(AGG, P, nullptr, WP4, b2b, H, SUM, SQ);
    bn_finalize<64><<<1, 256, 0, stream>>>(SUM, SQ, g2, be2, SCALE, SHIFT);
    bn_apply<64><<<(NODES * 64 + 255) / 256, 256, 0, stream>>>(H, SCALE, SHIFT);

    // ---- layer 3 (64 -> 32 -> 32) ----
    csr_agg<64><<<AB, 256, 0, stream>>>(H, P, rowstart, csrc, AGG);
    gemm_kernel<64, 32, true, false><<<GB, 256, 0, stream>>>(H, P, AGG, WP5, b3a, AGG, nullptr, nullptr);
    hipMemsetAsync(SUM, 0, 512 * sizeof(float), stream);
    gemm_kernel<32, 32, false, true><<<GB, 256, 0, stream>>>(AGG, P, nullptr, WP6, b3b, H, SUM, SQ);
    bn_finalize<32><<<1, 256, 0, stream>>>(SUM, SQ, g3, be3, SCALE, SHIFT);
    bn_apply<32><<<(NODES * 32 + 255) / 256, 256, 0, stream>>>(H, SCALE, SHIFT);

    // ---- pool + head ----
    hipMemsetAsync(G, 0, GRAPHS * 32 * sizeof(float), stream);
    pool_kernel<<<(NODES * 32 + 255) / 256, 256, 0, stream>>>(H, batch, G);
    head_kernel<<<(GRAPHS + 255) / 256, 256, 0, stream>>>(G, fw1, fb1, fw2, fb2, ow, ob, out);
}

// Round 4
// 914.486 us; speedup vs baseline: 3.6694x; 3.6694x over previous
//
#include <hip/hip_runtime.h>

#define NODES  50000
#define EDGES  800000
#define GRAPHS 1024
#define P      200      // uniform row pitch (floats) for node-feature buffers

// ---------------------------------------------------------------------------
// CSR build
// ---------------------------------------------------------------------------
__global__ void hist_kernel(const int* __restrict__ dst, int* __restrict__ deg) {
    int e = blockIdx.x * blockDim.x + threadIdx.x;
    if (e < EDGES) atomicAdd(&deg[dst[e]], 1);
}

__global__ void scan_kernel(const int* __restrict__ deg,
                            int* __restrict__ rowstart, int* __restrict__ cursor) {
    __shared__ int part[1024];
    int t = threadIdx.x;
    const int CH = (NODES + 1023) / 1024;   // 49
    int base = t * CH;
    int s = 0;
    for (int i = 0; i < CH; i++) {
        int n = base + i;
        if (n < NODES) s += deg[n];
    }
    part[t] = s;
    __syncthreads();
    for (int off = 1; off < 1024; off <<= 1) {
        int v = 0;
        if (t >= off) v = part[t - off];
        __syncthreads();
        if (t >= off) part[t] += v;
        __syncthreads();
    }
    int run = (t == 0) ? 0 : part[t - 1];
    for (int i = 0; i < CH; i++) {
        int n = base + i;
        if (n < NODES) {
            rowstart[n] = run;
            cursor[n]   = run;
            run += deg[n];
        }
    }
    if (t == 0) rowstart[NODES] = EDGES;
}

__global__ void scatter_kernel(const int* __restrict__ src, const int* __restrict__ dst,
                               int* __restrict__ cursor, int* __restrict__ csrc) {
    int e = blockIdx.x * blockDim.x + threadIdx.x;
    if (e < EDGES) {
        int p = atomicAdd(&cursor[dst[e]], 1);
        csrc[p] = src[e];
    }
}

// ---------------------------------------------------------------------------
// Weight pad: dst[k][n] (pitch NP=2^npshift) = src[k][n] or 0
// ---------------------------------------------------------------------------
__global__ void pad_w_kernel(const float* __restrict__ src, int K, int N, int npshift,
                             float* __restrict__ dst) {
    int idx = blockIdx.x * blockDim.x + threadIdx.x;
    int NP = 1 << npshift;
    if (idx >= K * NP) return;
    int k = idx >> npshift, n = idx & (NP - 1);
    dst[idx] = (n < N) ? src[k * N + n] : 0.0f;
}

// ---------------------------------------------------------------------------
// Aggregation: one wave per destination node, register accumulation, no atomics
// ---------------------------------------------------------------------------
template<int D>
__global__ void csr_agg(const float* __restrict__ feat, int fpitch,
                        const int* __restrict__ rowstart, const int* __restrict__ csrc,
                        float* __restrict__ agg) {
    int wid  = (blockIdx.x * blockDim.x + threadIdx.x) >> 6;
    int lane = threadIdx.x & 63;
    if (wid >= NODES) return;
    constexpr int NI = (D + 63) / 64;
    float s[NI];
#pragma unroll
    for (int i = 0; i < NI; i++) s[i] = 0.0f;
    int r0 = rowstart[wid], r1 = rowstart[wid + 1];
    for (int r = r0; r < r1; r++) {
        int sn = csrc[r];
        const float* fp = feat + (size_t)sn * fpitch;
#pragma unroll
        for (int i = 0; i < NI; i++) {
            int c = lane + 64 * i;
            if (c < D) s[i] += fp[c];
        }
    }
    float* ap = agg + (size_t)wid * P;
#pragma unroll
    for (int i = 0; i < NI; i++) {
        int c = lane + 64 * i;
        if (c < D) ap[c] = s[i];
    }
}

// ---------------------------------------------------------------------------
// GEMM: OUT[m][n] = relu( (X[m]+A2[m]) @ W + B ), optional BN-stat epilogue.
// 64-row tile / block. W pre-padded to pitch NP (zeros beyond N, and we mask
// k>=K rows to zero at stage time so As garbage never contributes).
// KT=16 for NP=256 keeps LDS ~23KB -> 4+ blocks/CU resident.
// In-place OUT==A2 safe: reads of own rows all precede epilogue writes.
// ---------------------------------------------------------------------------
template<int K, int N, bool ADD2, bool STATS>
__launch_bounds__(256)
__global__ void gemm_kernel(const float* __restrict__ X, int xpitch,
                            const float* __restrict__ A2,
                            const float* __restrict__ WP,   // K x NP, padded
                            const float* __restrict__ B,
                            float* __restrict__ OUT,
                            float* __restrict__ gsum, float* __restrict__ gsq) {
    constexpr int NP = ((N + 63) / 64) * 64;       // 64 or 256
    constexpr int KT = (NP == 256) ? 16 : 32;      // LDS budget vs barrier count
    constexpr int NC = (K + KT - 1) / KT;
    constexpr int G  = NP / 64;
    constexpr int AS = KT + 4;                      // As row stride (bank-friendly)
    constexpr int NP4 = NP / 4;                     // float4s per W row
    constexpr int AIT = (64 * KT) / 256;            // As scalar loads/thread
    constexpr int WIT = (KT * NP4) / 256;           // Ws float4 loads/thread
    __shared__ __align__(16) float As[64 * AS];
    __shared__ __align__(16) float Ws[KT * NP];
    __shared__ float shSum[STATS ? NP : 4];
    __shared__ float shSq [STATS ? NP : 4];

    const int tid = threadIdx.x;
    const int tx = tid & 15, ty = tid >> 4;
    const int node0 = blockIdx.x * 64;

    if (STATS && tid < NP) { shSum[tid] = 0.0f; shSq[tid] = 0.0f; }

    float acc[4][G][4];
#pragma unroll
    for (int g = 0; g < G; g++) {
#pragma unroll
        for (int e = 0; e < 4; e++) {
            int n = tx * 4 + 64 * g + e;
            float bv = (n < N) ? B[n] : 0.0f;
#pragma unroll
            for (int i = 0; i < 4; i++) acc[i][g][e] = bv;
        }
    }

    for (int c = 0; c < NC; c++) {
        const int kbase = c * KT;
        // ---- stage A chunk: rows [node0,node0+64), cols [kbase,kbase+KT) ----
#pragma unroll
        for (int it = 0; it < AIT; it++) {
            int idx = tid + 256 * it;
            int r = idx / KT, cc = idx % KT;
            int gn = node0 + r, gk = kbase + cc;
            float v = 0.0f;
            if (gn < NODES && gk < K) {
                v = X[(size_t)gn * xpitch + gk];
                if (ADD2) v += A2[(size_t)gn * P + gk];
            }
            As[r * AS + cc] = v;
        }
        // ---- stage W chunk (float4, rows masked to zero for gk>=K) ----
#pragma unroll
        for (int it = 0; it < WIT; it++) {
            int idx4 = tid + 256 * it;
            int kk = idx4 / NP4, n4 = idx4 % NP4;
            int gk = kbase + kk;
            float4 v = make_float4(0.0f, 0.0f, 0.0f, 0.0f);
            if (gk < K) v = *(const float4*)&WP[gk * NP + n4 * 4];
            *(float4*)&Ws[kk * NP + n4 * 4] = v;
        }
        __syncthreads();

        // ---- compute ----
#pragma unroll
        for (int kk = 0; kk < KT; kk += 4) {
            float a[4][4];
#pragma unroll
            for (int i = 0; i < 4; i++) {
                float4 av = *(const float4*)&As[(ty + 16 * i) * AS + kk];
                a[i][0] = av.x; a[i][1] = av.y; a[i][2] = av.z; a[i][3] = av.w;
            }
#pragma unroll
            for (int q = 0; q < 4; q++) {
#pragma unroll
                for (int g = 0; g < G; g++) {
                    float4 w = *(const float4*)&Ws[(kk + q) * NP + tx * 4 + 64 * g];
#pragma unroll
                    for (int i = 0; i < 4; i++) {
                        acc[i][g][0] = fmaf(a[i][q], w.x, acc[i][g][0]);
                        acc[i][g][1] = fmaf(a[i][q], w.y, acc[i][g][1]);
                        acc[i][g][2] = fmaf(a[i][q], w.z, acc[i][g][2]);
                        acc[i][g][3] = fmaf(a[i][q], w.w, acc[i][g][3]);
                    }
                }
            }
        }
        __syncthreads();
    }

    // ---- epilogue: relu, float4 store, stats ----
#pragma unroll
    for (int g = 0; g < G; g++) {
        int nb = tx * 4 + 64 * g;
        float rv[4][4];
#pragma unroll
        for (int i = 0; i < 4; i++)
#pragma unroll
            for (int e = 0; e < 4; e++) rv[i][e] = fmaxf(acc[i][g][e], 0.0f);
#pragma unroll
        for (int i = 0; i < 4; i++) {
            int gn = node0 + ty + 16 * i;
            if (gn < NODES) {
                if (nb + 3 < N) {
                    *(float4*)&OUT[(size_t)gn * P + nb] =
                        make_float4(rv[i][0], rv[i][1], rv[i][2], rv[i][3]);
                } else {
#pragma unroll
                    for (int e = 0; e < 4; e++)
                        if (nb + e < N) OUT[(size_t)gn * P + nb + e] = rv[i][e];
                }
            }
        }
        if (STATS) {
#pragma unroll
            for (int e = 0; e < 4; e++) {
                int n = nb + e;
                if (n < N) {
                    float s = 0.0f, q = 0.0f;
#pragma unroll
                    for (int i = 0; i < 4; i++) {
                        if (node0 + ty + 16 * i < NODES) {
                            s += rv[i][e]; q += rv[i][e] * rv[i][e];
                        }
                    }
                    atomicAdd(&shSum[n], s); atomicAdd(&shSq[n], q);
                }
            }
        }
    }
    if (STATS) {
        __syncthreads();
        for (int n = tid; n < N; n += 256) {
            atomicAdd(&gsum[n], shSum[n]);
            atomicAdd(&gsq[n], shSq[n]);
        }
    }
}

// ---------------------------------------------------------------------------
// BN finalize + apply
// ---------------------------------------------------------------------------
template<int N>
__global__ void bn_finalize(const float* __restrict__ sum, const float* __restrict__ sq,
                            const float* __restrict__ gamma, const float* __restrict__ beta,
                            float* __restrict__ scale, float* __restrict__ shift) {
    int n = threadIdx.x;
    if (n < N) {
        float mean = sum[n] * (1.0f / NODES);
        float var  = sq[n] * (1.0f / NODES) - mean * mean;
        var = var < 0.0f ? 0.0f : var;
        float sc = gamma[n] * rsqrtf(var + 1e-5f);
        scale[n] = sc;
        shift[n] = beta[n] - mean * sc;
    }
}

template<int N>
__global__ void bn_apply(float* __restrict__ h, const float* __restrict__ scale,
                         const float* __restrict__ shift) {
    long idx = (long)blockIdx.x * blockDim.x + threadIdx.x;
    if (idx >= (long)NODES * N) return;
    int node = (int)(idx / N);
    int c = (int)(idx - (long)node * N);
    size_t o = (size_t)node * P + c;
    h[o] = fmaf(h[o], scale[c], shift[c]);
}

// ---------------------------------------------------------------------------
// Pool + head MLP
// ---------------------------------------------------------------------------
__global__ void pool_kernel(const float* __restrict__ h, const int* __restrict__ batch,
                            float* __restrict__ g) {
    int idx = blockIdx.x * blockDim.x + threadIdx.x;
    if (idx >= NODES * 32) return;
    int n = idx >> 5, f = idx & 31;
    atomicAdd(&g[batch[n] * 32 + f], h[(size_t)n * P + f]);
}

__global__ void head_kernel(const float* __restrict__ g,
                            const float* __restrict__ fw1, const float* __restrict__ fb1,
                            const float* __restrict__ fw2, const float* __restrict__ fb2,
                            const float* __restrict__ ow, const float* __restrict__ ob,
                            float* __restrict__ out) {
    int gi = blockIdx.x * blockDim.x + threadIdx.x;
    if (gi >= GRAPHS) return;
    float v[32];
#pragma unroll
    for (int k = 0; k < 32; k++) v[k] = g[gi * 32 + k];
    float a1[16];
#pragma unroll
    for (int o = 0; o < 16; o++) {
        float s = fb1[o];
#pragma unroll
        for (int k = 0; k < 32; k++) s = fmaf(v[k], fw1[k * 16 + o], s);
        a1[o] = s > 0.0f ? s : 0.0f;
    }
    float a2[8];
#pragma unroll
    for (int o = 0; o < 8; o++) {
        float s = fb2[o];
#pragma unroll
        for (int k = 0; k < 16; k++) s = fmaf(a1[k], fw2[k * 8 + o], s);
        a2[o] = s > 0.0f ? s : 0.0f;
    }
#pragma unroll
    for (int o = 0; o < 2; o++) {
        float s = ob[o];
#pragma unroll
        for (int k = 0; k < 8; k++) s = fmaf(a2[k], ow[k * 2 + o], s);
        out[gi * 2 + o] = s;
    }
}

// ---------------------------------------------------------------------------
extern "C" void kernel_launch(void* const* d_in, const int* in_sizes, int n_in,
                              void* d_out, int out_size, void* d_ws, size_t ws_size,
                              hipStream_t stream) {
    const float* x     = (const float*)d_in[0];
    const int*   ei    = (const int*)d_in[1];
    const int*   batch = (const int*)d_in[2];
    const float *w1a = (const float*)d_in[3],  *b1a = (const float*)d_in[4];
    const float *w1b = (const float*)d_in[5],  *b1b = (const float*)d_in[6];
    const float *g1  = (const float*)d_in[7],  *be1 = (const float*)d_in[8];
    const float *w2a = (const float*)d_in[9],  *b2a = (const float*)d_in[10];
    const float *w2b = (const float*)d_in[11], *b2b = (const float*)d_in[12];
    const float *g2  = (const float*)d_in[13], *be2 = (const float*)d_in[14];
    const float *w3a = (const float*)d_in[15], *b3a = (const float*)d_in[16];
    const float *w3b = (const float*)d_in[17], *b3b = (const float*)d_in[18];
    const float *g3  = (const float*)d_in[19], *be3 = (const float*)d_in[20];
    const float *fw1 = (const float*)d_in[21], *fb1 = (const float*)d_in[22];
    const float *fw2 = (const float*)d_in[23], *fb2 = (const float*)d_in[24];
    const float *ow  = (const float*)d_in[25], *ob  = (const float*)d_in[26];
    const int* src = ei;
    const int* dst = ei + EDGES;

    float* ws    = (float*)d_ws;
    float* AGG   = ws;                                  // 50000 x 200
    float* H     = ws + (size_t)NODES * P;              // 50000 x 200
    float* SUM   = ws + (size_t)2 * NODES * P;          // 256
    float* SQ    = SUM + 256;
    float* SCALE = SUM + 512;
    float* SHIFT = SUM + 768;
    float* G     = SUM + 1024;                          // 1024 x 32
    int*   deg      = (int*)(G + GRAPHS * 32);          // 50000
    int*   rowstart = deg + NODES;                      // 50001
    int*   cursor   = rowstart + NODES + 1;             // 50000
    int*   csrc     = cursor + NODES;                   // 800000
    float* WP1 = (float*)(csrc + EDGES);                // 114 x 256
    float* WP2 = WP1 + 114 * 256;                       // 198 x 256
    float* WP3 = WP2 + 198 * 256;                       // 198 x 64
    float* WP4 = WP3 + 198 * 64;                        // 64 x 64
    float* WP5 = WP4 + 64 * 64;                         // 64 x 64
    float* WP6 = WP5 + 64 * 64;                         // 32 x 64
    float* out = (float*)d_out;

    const int GB = (NODES + 63) / 64;        // gemm blocks
    const int AB = (NODES * 64 + 255) / 256; // agg blocks (wave per node)
    const int EB = (EDGES + 255) / 256;

    // ---- weight padding (once per launch) ----
    pad_w_kernel<<<(114 * 256 + 255) / 256, 256, 0, stream>>>(w1a, 114, 198, 8, WP1);
    pad_w_kernel<<<(198 * 256 + 255) / 256, 256, 0, stream>>>(w1b, 198, 198, 8, WP2);
    pad_w_kernel<<<(198 * 64 + 255) / 256, 256, 0, stream>>>(w2a, 198, 64, 6, WP3);
    pad_w_kernel<<<(64 * 64 + 255) / 256, 256, 0, stream>>>(w2b, 64, 64, 6, WP4);
    pad_w_kernel<<<(64 * 64 + 255) / 256, 256, 0, stream>>>(w3a, 64, 32, 6, WP5);
    pad_w_kernel<<<(32 * 64 + 255) / 256, 256, 0, stream>>>(w3b, 32, 32, 6, WP6);

    // ---- CSR build (shared by all 3 layers) ----
    hipMemsetAsync(deg, 0, NODES * sizeof(int), stream);
    hist_kernel<<<EB, 256, 0, stream>>>(dst, deg);
    scan_kernel<<<1, 1024, 0, stream>>>(deg, rowstart, cursor);
    scatter_kernel<<<EB, 256, 0, stream>>>(src, dst, cursor, csrc);

    // ---- layer 1 (114 -> 198 -> 198) ----
    csr_agg<114><<<AB, 256, 0, stream>>>(x, 114, rowstart, csrc, AGG);
    gemm_kernel<114, 198, true, false><<<GB, 256, 0, stream>>>(x, 114, AGG, WP1, b1a, AGG, nullptr, nullptr);
    hipMemsetAsync(SUM, 0, 512 * sizeof(float), stream);
    gemm_kernel<198, 198, false, true><<<GB, 256, 0, stream>>>(AGG, P, nullptr, WP2, b1b, H, SUM, SQ);
    bn_finalize<198><<<1, 256, 0, stream>>>(SUM, SQ, g1, be1, SCALE, SHIFT);
    bn_apply<198><<<(NODES * 198 + 255) / 256, 256, 0, stream>>>(H, SCALE, SHIFT);

    // ---- layer 2 (198 -> 64 -> 64) ----
    csr_agg<198><<<AB, 256, 0, stream>>>(H, P, rowstart, csrc, AGG);
    gemm_kernel<198, 64, true, false><<<GB, 256, 0, stream>>>(H, P, AGG, WP3, b2a, AGG, nullptr, nullptr);
    hipMemsetAsync(SUM, 0, 512 * sizeof(float), stream);
    gemm_kernel<64, 64, false, true><<<GB, 256, 0, stream>>>(AGG, P, nullptr, WP4, b2b, H, SUM, SQ);
    bn_finalize<64><<<1, 256, 0, stream>>>(SUM, SQ, g2, be2, SCALE, SHIFT);
    bn_apply<64><<<(NODES * 64 + 255) / 256, 256, 0, stream>>>(H, SCALE, SHIFT);

    // ---- layer 3 (64 -> 32 -> 32) ----
    csr_agg<64><<<AB, 256, 0, stream>>>(H, P, rowstart, csrc, AGG);
    gemm_kernel<64, 32, true, false><<<GB, 256, 0, stream>>>(H, P, AGG, WP5, b3a, AGG, nullptr, nullptr);
    hipMemsetAsync(SUM, 0, 512 * sizeof(float), stream);
    gemm_kernel<32, 32, false, true><<<GB, 256, 0, stream>>>(AGG, P, nullptr, WP6, b3b, H, SUM, SQ);
    bn_finalize<32><<<1, 256, 0, stream>>>(SUM, SQ, g3, be3, SCALE, SHIFT);
    bn_apply<32><<<(NODES * 32 + 255) / 256, 256, 0, stream>>>(H, SCALE, SHIFT);

    // ---- pool + head ----
    hipMemsetAsync(G, 0, GRAPHS * 32 * sizeof(float), stream);
    pool_kernel<<<(NODES * 32 + 255) / 256, 256, 0, stream>>>(H, batch, G);
    head_kernel<<<(GRAPHS + 255) / 256, 256, 0, stream>>>(G, fw1, fb1, fw2, fb2, ow, ob, out);
}